// Round 5
// baseline (273.142 us; speedup 1.0000x reference)
//
#include <hip/hip_runtime.h>
#include <hip/hip_bf16.h>

#define K_DIM 512
#define N_DIM 512

typedef __attribute__((ext_vector_type(8))) short s8v;   // 8 bf16 bit-patterns (4 VGPR)
typedef __attribute__((ext_vector_type(4))) short s4v;
typedef __attribute__((ext_vector_type(4))) float f4v;

__device__ __forceinline__ short f2bf(float f) {
  union { float f; unsigned u; } v; v.f = f;
  unsigned r = (v.u + 0x7FFFu + ((v.u >> 16) & 1u)) >> 16;  // RNE
  return (short)r;
}
__device__ __forceinline__ float bflo(unsigned u) {
  union { unsigned u; float f; } v; v.u = u << 16; return v.f;
}
__device__ __forceinline__ float bfhi(unsigned u) {
  union { unsigned u; float f; } v; v.u = u & 0xffff0000u; return v.f;
}
// pack 2 f32 -> 2 bf16 (RNE), one instruction
__device__ __forceinline__ unsigned cvt_pk(float lo, float hi) {
  unsigned r;
  asm("v_cvt_pk_bf16_f32 %0, %1, %2" : "=v"(r) : "v"(lo), "v"(hi));
  return r;
}

// async global->LDS, 16B per lane. LDS dest = wave-uniform base (HW adds lane*16);
// global src is per-lane.
__device__ __forceinline__ void gload16(const void* g, void* l) {
  __builtin_amdgcn_global_load_lds(
      (const __attribute__((address_space(1))) void*)g,
      (__attribute__((address_space(3))) void*)l, 16, 0, 0);
}

// Detect whether edge_index arrived as int64 (odd int32 words all zero) or int32.
__global__ void k_flag(const int* __restrict__ e32, int* __restrict__ flag) {
  int t = threadIdx.x;
  int v = e32[2 * t + 1];
  unsigned long long m = __ballot(v == 0);
  if (t == 0) flag[0] = (m == ~0ULL) ? 1 : 0;
}

__global__ void k_convW(const float* __restrict__ W, short* __restrict__ Wb) {
  int i = (blockIdx.x * blockDim.x + threadIdx.x) * 4;
  float4 f = *(const float4*)(W + i);
  s4v s; s[0] = f2bf(f.x); s[1] = f2bf(f.y); s[2] = f2bf(f.z); s[3] = f2bf(f.w);
  *(s4v*)(Wb + i) = s;
}

__global__ void k_hist(const int* __restrict__ e32, const int* __restrict__ flag,
                       int* __restrict__ outdeg, int* __restrict__ indeg, int E) {
  int i = blockIdx.x * blockDim.x + threadIdx.x;
  if (i >= E) return;
  int st = flag[0] ? 2 : 1;
  int r = e32[(size_t)i * st];
  int c = e32[(size_t)(E + i) * st];
  atomicAdd(&outdeg[r], 1);
  atomicAdd(&indeg[c], 1);
}

__global__ void k_dis(const int* __restrict__ outdeg, float* __restrict__ dis, int n) {
  int i = blockIdx.x * blockDim.x + threadIdx.x;
  if (i < n) dis[i] = rsqrtf((float)(outdeg[i] + 1));  // +1 self-loop
}

__global__ void k_scan_a(const int* __restrict__ in, int* __restrict__ part, int n) {
  __shared__ int sm[256];
  int i = blockIdx.x * 256 + threadIdx.x;
  sm[threadIdx.x] = (i < n) ? in[i] : 0;
  __syncthreads();
  for (int off = 128; off > 0; off >>= 1) {
    if (threadIdx.x < off) sm[threadIdx.x] += sm[threadIdx.x + off];
    __syncthreads();
  }
  if (threadIdx.x == 0) part[blockIdx.x] = sm[0];
}

__global__ void k_scan_b(int* __restrict__ part, int nb, int* __restrict__ row_start, int n) {
  __shared__ int sm[256];
  int t = threadIdx.x;
  int v = (t < nb) ? part[t] : 0;
  sm[t] = v; __syncthreads();
  for (int off = 1; off < 256; off <<= 1) {
    int a = (t >= off) ? sm[t - off] : 0;
    __syncthreads();
    sm[t] += a;
    __syncthreads();
  }
  part[t] = sm[t] - v;                  // exclusive block offsets
  if (t == 255) row_start[n] = sm[255]; // grand total (= E)
}

__global__ void k_scan_c(const int* __restrict__ in, const int* __restrict__ part,
                         int* __restrict__ row_start, int* __restrict__ cursor, int n) {
  __shared__ int sm[256];
  int i = blockIdx.x * 256 + threadIdx.x;
  int v = (i < n) ? in[i] : 0;
  sm[threadIdx.x] = v; __syncthreads();
  for (int off = 1; off < 256; off <<= 1) {
    int a = (threadIdx.x >= off) ? sm[threadIdx.x - off] : 0;
    __syncthreads();
    sm[threadIdx.x] += a;
    __syncthreads();
  }
  if (i < n) {
    int excl = part[blockIdx.x] + sm[threadIdx.x] - v;
    row_start[i] = excl;
    cursor[i] = excl;
  }
}

__global__ void k_fill(const int* __restrict__ e32, const int* __restrict__ flag,
                       int* __restrict__ cursor, int* __restrict__ csr, int E) {
  int i = blockIdx.x * blockDim.x + threadIdx.x;
  if (i >= E) return;
  int st = flag[0] ? 2 : 1;
  int r = e32[(size_t)i * st];
  int c = e32[(size_t)(E + i) * st];
  int p = atomicAdd(&cursor[c], 1);
  csr[p] = r;
}

// h[M][512] (bf16) = x[M][512] (f32) @ Wb[512][512]^T (bf16) + bias
// 128x128 tile, BK=32 (16 K-steps), 4 waves (2x2), wave 64x64 = 4x4 frags.
// LDS: pair-row layout [64][64]: lds_row R>>1 holds x-rows 2R,2R+1; 16B chunks
// XOR-swizzled by (lds_row&7). A: coalesced f32 loads + cvt_pk + ds_write_b64
// (conflict-free). B: global_load_lds with pre-swizzled global source (rule 21).
// Double-buffered, 2-phase. Bijective chunked XCD swizzle (m204).
__global__ __launch_bounds__(256) void k_gemm(const float* __restrict__ x,
    const short* __restrict__ Wb, const float* __restrict__ bias,
    short* __restrict__ h, int M) {
  __shared__ __align__(16) short As[2][64][64];  // 8KB per buffer
  __shared__ __align__(16) short Bs[2][64][64];
  // --- XCD-chunked bijective swizzle (8 XCDs) ---
  int nwg = gridDim.x;
  int orig = blockIdx.x;
  int q8 = nwg >> 3, r8 = nwg & 7;
  int xcd = orig & 7, pos = orig >> 3;
  int swz = (xcd < r8 ? xcd * (q8 + 1) : r8 * (q8 + 1) + (xcd - r8) * q8) + pos;
  const int n0 = (swz & 3) * 128;    // N fastest within swz chunk
  const int m0 = (swz >> 2) * 128;

  const int tid = threadIdx.x;
  const int lane = tid & 63;
  const int wv = tid >> 6, wr = wv >> 1, wc = wv & 1;
  const int la = lane & 15, lg = lane >> 4;

  // ---- B staging: 2 gload rounds/tile. id=r*256+tid -> lds slot id (16B).
  // lds_row_s=id>>3, pch=id&7; lch=pch^(lds_row_s&7); src row=2*lds_row_s+(lch>>2),
  // src col chunk=lch&3.
  const short* bsrc[2];
  int bdoff[2];
  #pragma unroll
  for (int r = 0; r < 2; ++r) {
    int id = r * 256 + tid;
    int lrs = id >> 3, pch = id & 7;
    int lch = pch ^ (lrs & 7);
    bsrc[r] = Wb + (size_t)(n0 + 2 * lrs + (lch >> 2)) * K_DIM + (lch & 3) * 8;
    bdoff[r] = r * 4096 + (tid & 192) * 16;  // wave-uniform byte base
  }

  // ---- A staging: 4 coalesced f32 rounds/tile. id=r*256+tid covers x-row
  // id>>3 (8 lanes/row -> 128B segments), float-chunk tid&7.
  const float* asrc[4];
  int aoff[4];
  bool aok[4];
  {
    int fch = tid & 7;
    int par = (tid >> 3) & 1;
    #pragma unroll
    for (int r = 0; r < 4; ++r) {
      int xrow = r * 32 + (tid >> 3);           // 0..127
      asrc[r] = x + (size_t)(m0 + xrow) * K_DIM + fch * 4;
      aok[r] = (m0 + xrow) < M;
      int lrow = r * 16 + (tid >> 4);           // xrow>>1
      int lch = par * 4 + (fch >> 1);
      int pch = lch ^ (lrow & 7);
      aoff[r] = lrow * 128 + pch * 16 + (fch & 1) * 8;
    }
  }

  // ---- fragment read offsets (per-thread constants)
  int aro[4], bro[4];
  #pragma unroll
  for (int i = 0; i < 4; ++i) {
    int Ra = 64 * wr + 16 * i + la;
    aro[i] = (Ra >> 1) * 128 + ((((Ra & 1) * 4 + lg) ^ ((Ra >> 1) & 7)) * 16);
    int Rb = 64 * wc + 16 * i + la;
    bro[i] = (Rb >> 1) * 128 + ((((Rb & 1) * 4 + lg) ^ ((Rb >> 1) & 7)) * 16);
  }

  f4v acc[4][4] = {};

  auto stage_a = [&](int buf, int kk) {
    #pragma unroll
    for (int r = 0; r < 4; ++r) {
      float4 f = aok[r] ? *(const float4*)(asrc[r] + kk) : float4{0, 0, 0, 0};
      uint2 w;
      w.x = cvt_pk(f.x, f.y);
      w.y = cvt_pk(f.z, f.w);
      *(uint2*)((char*)As + buf * 8192 + aoff[r]) = w;
    }
  };
  auto stage_b = [&](int buf, int kk) {
    #pragma unroll
    for (int r = 0; r < 2; ++r)
      gload16(bsrc[r] + kk, (char*)Bs + buf * 8192 + bdoff[r]);
  };

  // prologue: tile 0 -> buffer 0
  stage_b(0, 0);
  stage_a(0, 0);
  __syncthreads();

  for (int kt = 0; kt < 16; ++kt) {
    const int cur = kt & 1;
    const int nxt = cur ^ 1;
    if (kt < 15) stage_b(nxt, (kt + 1) * 32);
    s8v af[4], bf[4];
    const char* ab = (const char*)As + cur * 8192;
    const char* bb = (const char*)Bs + cur * 8192;
    #pragma unroll
    for (int i = 0; i < 4; ++i) af[i] = *(const s8v*)(ab + aro[i]);
    #pragma unroll
    for (int j = 0; j < 4; ++j) bf[j] = *(const s8v*)(bb + bro[j]);
    #pragma unroll
    for (int i = 0; i < 4; ++i)
      #pragma unroll
      for (int j = 0; j < 4; ++j)
        acc[i][j] = __builtin_amdgcn_mfma_f32_16x16x32_bf16(af[i], bf[j], acc[i][j], 0, 0, 0);
    if (kt < 15) stage_a(nxt, (kt + 1) * 32);
    __syncthreads();  // drains vmcnt/lgkm: next tile staged, cur reads done
  }

  #pragma unroll
  for (int i = 0; i < 4; ++i) {
    #pragma unroll
    for (int j = 0; j < 4; ++j) {
      int col = n0 + 64 * wc + 16 * j + la;
      float bv = bias[col];
      #pragma unroll
      for (int r = 0; r < 4; ++r) {
        int row = m0 + 64 * wr + 16 * i + lg * 4 + r;
        if (row < M) h[(size_t)row * N_DIM + col] = f2bf(acc[i][j][r] + bv);
      }
    }
  }
}

__device__ __forceinline__ void acc8(float* acc, uint4 rv, float wv) {
  acc[0] += wv * bflo(rv.x); acc[1] += wv * bfhi(rv.x);
  acc[2] += wv * bflo(rv.y); acc[3] += wv * bfhi(rv.y);
  acc[4] += wv * bflo(rv.z); acc[5] += wv * bfhi(rv.z);
  acc[6] += wv * bflo(rv.w); acc[7] += wv * bfhi(rv.w);
}

// One wave per dst node; 8 gather rows in flight; scalar bounds.
__global__ __launch_bounds__(256) void k_scatter(const short* __restrict__ h,
    const float* __restrict__ dis, const int* __restrict__ row_start,
    const int* __restrict__ csr, float* __restrict__ out, int n) {
  int v = blockIdx.x * 4 + (threadIdx.x >> 6);
  if (v >= n) return;
  int lane = threadIdx.x & 63;
  const short* hl = h + lane * 8;
  float dv = dis[v];
  float acc[8];
  {
    uint4 r = *(const uint4*)(hl + (size_t)v * N_DIM);  // self-loop: dis[v]^2 * h[v]
    float w = dv * dv;
    acc[0] = w * bflo(r.x); acc[1] = w * bfhi(r.x);
    acc[2] = w * bflo(r.y); acc[3] = w * bfhi(r.y);
    acc[4] = w * bflo(r.z); acc[5] = w * bfhi(r.z);
    acc[6] = w * bflo(r.w); acc[7] = w * bfhi(r.w);
  }
  int s = __builtin_amdgcn_readfirstlane(row_start[v]);
  int e = __builtin_amdgcn_readfirstlane(row_start[v + 1]);
  int idx = s;
  for (; idx + 8 <= e; idx += 8) {
    int s0 = csr[idx],     s1 = csr[idx + 1], s2 = csr[idx + 2], s3 = csr[idx + 3];
    int s4 = csr[idx + 4], s5 = csr[idx + 5], s6 = csr[idx + 6], s7 = csr[idx + 7];
    float w0 = dis[s0] * dv, w1 = dis[s1] * dv, w2 = dis[s2] * dv, w3 = dis[s3] * dv;
    float w4 = dis[s4] * dv, w5 = dis[s5] * dv, w6 = dis[s6] * dv, w7 = dis[s7] * dv;
    uint4 r0 = *(const uint4*)(hl + (size_t)s0 * N_DIM);
    uint4 r1 = *(const uint4*)(hl + (size_t)s1 * N_DIM);
    uint4 r2 = *(const uint4*)(hl + (size_t)s2 * N_DIM);
    uint4 r3 = *(const uint4*)(hl + (size_t)s3 * N_DIM);
    uint4 r4 = *(const uint4*)(hl + (size_t)s4 * N_DIM);
    uint4 r5 = *(const uint4*)(hl + (size_t)s5 * N_DIM);
    uint4 r6 = *(const uint4*)(hl + (size_t)s6 * N_DIM);
    uint4 r7 = *(const uint4*)(hl + (size_t)s7 * N_DIM);
    acc8(acc, r0, w0); acc8(acc, r1, w1); acc8(acc, r2, w2); acc8(acc, r3, w3);
    acc8(acc, r4, w4); acc8(acc, r5, w5); acc8(acc, r6, w6); acc8(acc, r7, w7);
  }
  for (; idx + 4 <= e; idx += 4) {
    int s0 = csr[idx], s1 = csr[idx + 1], s2 = csr[idx + 2], s3 = csr[idx + 3];
    float w0 = dis[s0] * dv, w1 = dis[s1] * dv;
    float w2 = dis[s2] * dv, w3 = dis[s3] * dv;
    uint4 r0 = *(const uint4*)(hl + (size_t)s0 * N_DIM);
    uint4 r1 = *(const uint4*)(hl + (size_t)s1 * N_DIM);
    uint4 r2 = *(const uint4*)(hl + (size_t)s2 * N_DIM);
    uint4 r3 = *(const uint4*)(hl + (size_t)s3 * N_DIM);
    acc8(acc, r0, w0); acc8(acc, r1, w1); acc8(acc, r2, w2); acc8(acc, r3, w3);
  }
  for (; idx < e; ++idx) {
    int s0 = csr[idx];
    float w0 = dis[s0] * dv;
    uint4 r0 = *(const uint4*)(hl + (size_t)s0 * N_DIM);
    acc8(acc, r0, w0);
  }
  float* op = out + (size_t)v * N_DIM + lane * 8;
  float4 o0, o1;
  o0.x = fmaxf(acc[0], 0.f); o0.y = fmaxf(acc[1], 0.f);
  o0.z = fmaxf(acc[2], 0.f); o0.w = fmaxf(acc[3], 0.f);
  o1.x = fmaxf(acc[4], 0.f); o1.y = fmaxf(acc[5], 0.f);
  o1.z = fmaxf(acc[6], 0.f); o1.w = fmaxf(acc[7], 0.f);
  *(float4*)op = o0;
  *(float4*)(op + 4) = o1;
}

extern "C" void kernel_launch(void* const* d_in, const int* in_sizes, int n_in,
                              void* d_out, int out_size, void* d_ws, size_t ws_size,
                              hipStream_t stream) {
  const float* x = (const float*)d_in[0];
  const int* e32 = (const int*)d_in[1];
  const float* W = (const float*)d_in[2];
  const float* bias = (const float*)d_in[3];
  float* out = (float*)d_out;
  int M = in_sizes[0] / K_DIM;   // 50000
  int E = in_sizes[1] / 2;       // 400000

  char* ws = (char*)d_ws;
  size_t off = 0;
  auto alloc = [&](size_t bytes) {
    void* p = ws + off;
    off = (off + bytes + 255) & ~(size_t)255;
    return p;
  };
  short* Wb      = (short*)alloc((size_t)N_DIM * K_DIM * 2);
  short* h       = (short*)alloc((size_t)M * N_DIM * 2);
  float* dis     = (float*)alloc((size_t)M * 4);
  int*   outdeg  = (int*)alloc((size_t)M * 4);
  int*   indeg   = (int*)alloc((size_t)M * 4);
  int*   rstart  = (int*)alloc((size_t)(M + 1) * 4);
  int*   cursor  = (int*)alloc((size_t)M * 4);
  int*   part    = (int*)alloc(256 * 4);
  int*   csr     = (int*)alloc((size_t)E * 4);
  int*   flag    = (int*)alloc(4);
  if (off > ws_size) return;  // workspace too small: fail loudly via absmax

  (void)hipMemsetAsync(outdeg, 0, (size_t)M * 4, stream);
  (void)hipMemsetAsync(indeg, 0, (size_t)M * 4, stream);
  k_flag<<<1, 64, 0, stream>>>(e32, flag);
  k_convW<<<(N_DIM * K_DIM / 4 + 255) / 256, 256, 0, stream>>>(W, Wb);
  k_hist<<<(E + 255) / 256, 256, 0, stream>>>(e32, flag, outdeg, indeg, E);
  k_dis<<<(M + 255) / 256, 256, 0, stream>>>(outdeg, dis, M);
  int nscan = (M + 255) / 256;  // 196 (must be <= 256)
  k_scan_a<<<nscan, 256, 0, stream>>>(indeg, part, M);
  k_scan_b<<<1, 256, 0, stream>>>(part, nscan, rstart, M);
  k_scan_c<<<nscan, 256, 0, stream>>>(indeg, part, rstart, cursor, M);
  k_fill<<<(E + 255) / 256, 256, 0, stream>>>(e32, flag, cursor, csr, E);
  int nmc = (M + 127) / 128;     // 391 M-chunks
  k_gemm<<<nmc * 4, 256, 0, stream>>>(x, Wb, bias, h, M);
  k_scatter<<<(M + 3) / 4, 256, 0, stream>>>(h, dis, rstart, csr, out, M);
}

// Round 6
// 223.562 us; speedup vs baseline: 1.2218x; 1.2218x over previous
//
#include <hip/hip_runtime.h>
#include <hip/hip_bf16.h>

#define K_DIM 512
#define N_DIM 512

typedef __attribute__((ext_vector_type(8))) short s8v;   // 8 bf16 bit-patterns (4 VGPR)
typedef __attribute__((ext_vector_type(4))) short s4v;
typedef __attribute__((ext_vector_type(4))) float f4v;

__device__ __forceinline__ short f2bf(float f) {
  union { float f; unsigned u; } v; v.f = f;
  unsigned r = (v.u + 0x7FFFu + ((v.u >> 16) & 1u)) >> 16;  // RNE
  return (short)r;
}
__device__ __forceinline__ float bflo(unsigned u) {
  union { unsigned u; float f; } v; v.u = u << 16; return v.f;
}
__device__ __forceinline__ float bfhi(unsigned u) {
  union { unsigned u; float f; } v; v.u = u & 0xffff0000u; return v.f;
}

// async global->LDS, 16B per lane. LDS dest = wave-uniform base (HW adds lane*16);
// global src is per-lane.
__device__ __forceinline__ void gload16(const void* g, void* l) {
  __builtin_amdgcn_global_load_lds(
      (const __attribute__((address_space(1))) void*)g,
      (__attribute__((address_space(3))) void*)l, 16, 0, 0);
}

// Detect whether edge_index arrived as int64 (odd int32 words all zero) or int32.
__global__ void k_flag(const int* __restrict__ e32, int* __restrict__ flag) {
  int t = threadIdx.x;
  int v = e32[2 * t + 1];
  unsigned long long m = __ballot(v == 0);
  if (t == 0) flag[0] = (m == ~0ULL) ? 1 : 0;
}

__global__ void k_convW(const float* __restrict__ W, short* __restrict__ Wb) {
  int i = (blockIdx.x * blockDim.x + threadIdx.x) * 4;
  float4 f = *(const float4*)(W + i);
  s4v s; s[0] = f2bf(f.x); s[1] = f2bf(f.y); s[2] = f2bf(f.z); s[3] = f2bf(f.w);
  *(s4v*)(Wb + i) = s;
}

// x (f32) -> xb (bf16), vectorized 8/thread. Pure BW pass (~25us).
__global__ void k_convX(const float* __restrict__ x, short* __restrict__ xb,
                        long long total) {
  long long i = ((long long)blockIdx.x * 256 + threadIdx.x) * 8;
  if (i >= total) return;
  float4 f0 = *(const float4*)(x + i);
  float4 f1 = *(const float4*)(x + i + 4);
  s8v v;
  v[0] = f2bf(f0.x); v[1] = f2bf(f0.y); v[2] = f2bf(f0.z); v[3] = f2bf(f0.w);
  v[4] = f2bf(f1.x); v[5] = f2bf(f1.y); v[6] = f2bf(f1.z); v[7] = f2bf(f1.w);
  *(s8v*)(xb + i) = v;
}

__global__ void k_hist(const int* __restrict__ e32, const int* __restrict__ flag,
                       int* __restrict__ outdeg, int* __restrict__ indeg, int E) {
  int i = blockIdx.x * blockDim.x + threadIdx.x;
  if (i >= E) return;
  int st = flag[0] ? 2 : 1;
  int r = e32[(size_t)i * st];
  int c = e32[(size_t)(E + i) * st];
  atomicAdd(&outdeg[r], 1);
  atomicAdd(&indeg[c], 1);
}

__global__ void k_dis(const int* __restrict__ outdeg, float* __restrict__ dis, int n) {
  int i = blockIdx.x * blockDim.x + threadIdx.x;
  if (i < n) dis[i] = rsqrtf((float)(outdeg[i] + 1));  // +1 self-loop
}

__global__ void k_scan_a(const int* __restrict__ in, int* __restrict__ part, int n) {
  __shared__ int sm[256];
  int i = blockIdx.x * 256 + threadIdx.x;
  sm[threadIdx.x] = (i < n) ? in[i] : 0;
  __syncthreads();
  for (int off = 128; off > 0; off >>= 1) {
    if (threadIdx.x < off) sm[threadIdx.x] += sm[threadIdx.x + off];
    __syncthreads();
  }
  if (threadIdx.x == 0) part[blockIdx.x] = sm[0];
}

__global__ void k_scan_b(int* __restrict__ part, int nb, int* __restrict__ row_start, int n) {
  __shared__ int sm[256];
  int t = threadIdx.x;
  int v = (t < nb) ? part[t] : 0;
  sm[t] = v; __syncthreads();
  for (int off = 1; off < 256; off <<= 1) {
    int a = (t >= off) ? sm[t - off] : 0;
    __syncthreads();
    sm[t] += a;
    __syncthreads();
  }
  part[t] = sm[t] - v;                  // exclusive block offsets
  if (t == 255) row_start[n] = sm[255]; // grand total (= E)
}

__global__ void k_scan_c(const int* __restrict__ in, const int* __restrict__ part,
                         int* __restrict__ row_start, int* __restrict__ cursor, int n) {
  __shared__ int sm[256];
  int i = blockIdx.x * 256 + threadIdx.x;
  int v = (i < n) ? in[i] : 0;
  sm[threadIdx.x] = v; __syncthreads();
  for (int off = 1; off < 256; off <<= 1) {
    int a = (threadIdx.x >= off) ? sm[threadIdx.x - off] : 0;
    __syncthreads();
    sm[threadIdx.x] += a;
    __syncthreads();
  }
  if (i < n) {
    int excl = part[blockIdx.x] + sm[threadIdx.x] - v;
    row_start[i] = excl;
    cursor[i] = excl;
  }
}

__global__ void k_fill(const int* __restrict__ e32, const int* __restrict__ flag,
                       int* __restrict__ cursor, int* __restrict__ csr, int E) {
  int i = blockIdx.x * blockDim.x + threadIdx.x;
  if (i >= E) return;
  int st = flag[0] ? 2 : 1;
  int r = e32[(size_t)i * st];
  int c = e32[(size_t)(E + i) * st];
  int p = atomicAdd(&cursor[c], 1);
  csr[p] = r;
}

// h[M][512] (bf16) = xb[M][512] (bf16) @ Wb[512][512]^T (bf16) + bias
// m97-faithful: 128x128 tile, BK=32 (16 steps), 4 waves (2x2), wave 64x64.
// BOTH operands staged via global_load_lds w=16 into linear LDS [128][32];
// zero staging VALU in the K-loop. Double-buffered, one barrier per step.
// Bank conflicts on ds_read accepted (2-phase regime: staging dominates, m233).
__global__ __launch_bounds__(256, 3) void k_gemm(const short* __restrict__ xb,
    const short* __restrict__ Wb, const float* __restrict__ bias,
    short* __restrict__ h, int M) {
  __shared__ __align__(16) short As[2][128 * 32];  // 8KB per buffer
  __shared__ __align__(16) short Bs[2][128 * 32];
  // --- XCD-chunked bijective swizzle (8 XCDs, m204) ---
  int nwg = gridDim.x;
  int orig = blockIdx.x;
  int q8 = nwg >> 3, r8 = nwg & 7;
  int xcd = orig & 7, pos = orig >> 3;
  int swz = (xcd < r8 ? xcd * (q8 + 1) : r8 * (q8 + 1) + (xcd - r8) * q8) + pos;
  const int n0 = (swz & 3) * 128;    // N fastest within swz chunk
  const int m0 = (swz >> 2) * 128;

  const int tid = threadIdx.x;
  const int lane = tid & 63;
  const int wv = tid >> 6, wr = wv >> 1, wc = wv & 1;
  const int la = lane & 15, lg = lane >> 4;

  // staging: 2 rounds x 256 lanes x 16B cover 128 rows x 64B (BK=32 bf16)
  const short* ag[2];
  const short* bg[2];
  int doff[2];
  #pragma unroll
  for (int r = 0; r < 2; ++r) {
    int id = r * 256 + tid;
    int row = id >> 2;               // 0..127
    int ch = id & 3;                 // 16B chunk within row
    int arow = m0 + row; if (arow >= M) arow = M - 1;  // clamp: no OOB, no divergence
    ag[r] = xb + (size_t)arow * K_DIM + ch * 8;
    bg[r] = Wb + (size_t)(n0 + row) * K_DIM + ch * 8;
    doff[r] = (r * 256 + (tid & 192)) * 16;  // wave-uniform byte base
  }
  // fragment read offsets
  int aro[4], bro[4];
  #pragma unroll
  for (int i = 0; i < 4; ++i) {
    aro[i] = (64 * wr + 16 * i + la) * 64 + lg * 16;
    bro[i] = (64 * wc + 16 * i + la) * 64 + lg * 16;
  }

  f4v acc[4][4] = {};

  // prologue: k-tile 0 -> buffer 0
  #pragma unroll
  for (int r = 0; r < 2; ++r) {
    gload16(ag[r], (char*)As + doff[r]);
    gload16(bg[r], (char*)Bs + doff[r]);
  }
  __syncthreads();

  for (int kt = 0; kt < 16; ++kt) {
    const int cur = kt & 1;
    const int nxt = cur ^ 1;
    if (kt < 15) {
      const int kk = (kt + 1) * 32;
      #pragma unroll
      for (int r = 0; r < 2; ++r) {
        gload16(ag[r] + kk, (char*)As + nxt * 8192 + doff[r]);
        gload16(bg[r] + kk, (char*)Bs + nxt * 8192 + doff[r]);
      }
    }
    s8v af[4], bf[4];
    const char* ab = (const char*)As + cur * 8192;
    const char* bb = (const char*)Bs + cur * 8192;
    #pragma unroll
    for (int i = 0; i < 4; ++i) af[i] = *(const s8v*)(ab + aro[i]);
    #pragma unroll
    for (int j = 0; j < 4; ++j) bf[j] = *(const s8v*)(bb + bro[j]);
    #pragma unroll
    for (int i = 0; i < 4; ++i)
      #pragma unroll
      for (int j = 0; j < 4; ++j)
        acc[i][j] = __builtin_amdgcn_mfma_f32_16x16x32_bf16(af[i], bf[j], acc[i][j], 0, 0, 0);
    __syncthreads();  // drains vmcnt/lgkm: nxt staged, cur reads done
  }

  #pragma unroll
  for (int i = 0; i < 4; ++i) {
    #pragma unroll
    for (int j = 0; j < 4; ++j) {
      int col = n0 + 64 * wc + 16 * j + la;
      float bv = bias[col];
      #pragma unroll
      for (int r = 0; r < 4; ++r) {
        int row = m0 + 64 * wr + 16 * i + lg * 4 + r;
        if (row < M) h[(size_t)row * N_DIM + col] = f2bf(acc[i][j][r] + bv);
      }
    }
  }
}

__device__ __forceinline__ void acc8(float* acc, uint4 rv, float wv) {
  acc[0] += wv * bflo(rv.x); acc[1] += wv * bfhi(rv.x);
  acc[2] += wv * bflo(rv.y); acc[3] += wv * bfhi(rv.y);
  acc[4] += wv * bflo(rv.z); acc[5] += wv * bfhi(rv.z);
  acc[6] += wv * bflo(rv.w); acc[7] += wv * bfhi(rv.w);
}

// One wave per dst node; 8 gather rows in flight; scalar bounds.
__global__ __launch_bounds__(256) void k_scatter(const short* __restrict__ h,
    const float* __restrict__ dis, const int* __restrict__ row_start,
    const int* __restrict__ csr, float* __restrict__ out, int n) {
  int v = blockIdx.x * 4 + (threadIdx.x >> 6);
  if (v >= n) return;
  int lane = threadIdx.x & 63;
  const short* hl = h + lane * 8;
  float dv = dis[v];
  float acc[8];
  {
    uint4 r = *(const uint4*)(hl + (size_t)v * N_DIM);  // self-loop: dis[v]^2 * h[v]
    float w = dv * dv;
    acc[0] = w * bflo(r.x); acc[1] = w * bfhi(r.x);
    acc[2] = w * bflo(r.y); acc[3] = w * bfhi(r.y);
    acc[4] = w * bflo(r.z); acc[5] = w * bfhi(r.z);
    acc[6] = w * bflo(r.w); acc[7] = w * bfhi(r.w);
  }
  int s = __builtin_amdgcn_readfirstlane(row_start[v]);
  int e = __builtin_amdgcn_readfirstlane(row_start[v + 1]);
  int idx = s;
  for (; idx + 8 <= e; idx += 8) {
    int s0 = csr[idx],     s1 = csr[idx + 1], s2 = csr[idx + 2], s3 = csr[idx + 3];
    int s4 = csr[idx + 4], s5 = csr[idx + 5], s6 = csr[idx + 6], s7 = csr[idx + 7];
    float w0 = dis[s0] * dv, w1 = dis[s1] * dv, w2 = dis[s2] * dv, w3 = dis[s3] * dv;
    float w4 = dis[s4] * dv, w5 = dis[s5] * dv, w6 = dis[s6] * dv, w7 = dis[s7] * dv;
    uint4 r0 = *(const uint4*)(hl + (size_t)s0 * N_DIM);
    uint4 r1 = *(const uint4*)(hl + (size_t)s1 * N_DIM);
    uint4 r2 = *(const uint4*)(hl + (size_t)s2 * N_DIM);
    uint4 r3 = *(const uint4*)(hl + (size_t)s3 * N_DIM);
    uint4 r4 = *(const uint4*)(hl + (size_t)s4 * N_DIM);
    uint4 r5 = *(const uint4*)(hl + (size_t)s5 * N_DIM);
    uint4 r6 = *(const uint4*)(hl + (size_t)s6 * N_DIM);
    uint4 r7 = *(const uint4*)(hl + (size_t)s7 * N_DIM);
    acc8(acc, r0, w0); acc8(acc, r1, w1); acc8(acc, r2, w2); acc8(acc, r3, w3);
    acc8(acc, r4, w4); acc8(acc, r5, w5); acc8(acc, r6, w6); acc8(acc, r7, w7);
  }
  for (; idx + 4 <= e; idx += 4) {
    int s0 = csr[idx], s1 = csr[idx + 1], s2 = csr[idx + 2], s3 = csr[idx + 3];
    float w0 = dis[s0] * dv, w1 = dis[s1] * dv;
    float w2 = dis[s2] * dv, w3 = dis[s3] * dv;
    uint4 r0 = *(const uint4*)(hl + (size_t)s0 * N_DIM);
    uint4 r1 = *(const uint4*)(hl + (size_t)s1 * N_DIM);
    uint4 r2 = *(const uint4*)(hl + (size_t)s2 * N_DIM);
    uint4 r3 = *(const uint4*)(hl + (size_t)s3 * N_DIM);
    acc8(acc, r0, w0); acc8(acc, r1, w1); acc8(acc, r2, w2); acc8(acc, r3, w3);
  }
  for (; idx < e; ++idx) {
    int s0 = csr[idx];
    float w0 = dis[s0] * dv;
    uint4 r0 = *(const uint4*)(hl + (size_t)s0 * N_DIM);
    acc8(acc, r0, w0);
  }
  float* op = out + (size_t)v * N_DIM + lane * 8;
  float4 o0, o1;
  o0.x = fmaxf(acc[0], 0.f); o0.y = fmaxf(acc[1], 0.f);
  o0.z = fmaxf(acc[2], 0.f); o0.w = fmaxf(acc[3], 0.f);
  o1.x = fmaxf(acc[4], 0.f); o1.y = fmaxf(acc[5], 0.f);
  o1.z = fmaxf(acc[6], 0.f); o1.w = fmaxf(acc[7], 0.f);
  *(float4*)op = o0;
  *(float4*)(op + 4) = o1;
}

extern "C" void kernel_launch(void* const* d_in, const int* in_sizes, int n_in,
                              void* d_out, int out_size, void* d_ws, size_t ws_size,
                              hipStream_t stream) {
  const float* x = (const float*)d_in[0];
  const int* e32 = (const int*)d_in[1];
  const float* W = (const float*)d_in[2];
  const float* bias = (const float*)d_in[3];
  float* out = (float*)d_out;
  int M = in_sizes[0] / K_DIM;   // 50000
  int E = in_sizes[1] / 2;       // 400000

  char* ws = (char*)d_ws;
  size_t off = 0;
  auto alloc = [&](size_t bytes) {
    void* p = ws + off;
    off = (off + bytes + 255) & ~(size_t)255;
    return p;
  };
  short* Wb      = (short*)alloc((size_t)N_DIM * K_DIM * 2);
  short* h       = (short*)alloc((size_t)M * N_DIM * 2);
  float* dis     = (float*)alloc((size_t)M * 4);
  int*   outdeg  = (int*)alloc((size_t)M * 4);
  int*   indeg   = (int*)alloc((size_t)M * 4);
  int*   rstart  = (int*)alloc((size_t)(M + 1) * 4);
  int*   cursor  = (int*)alloc((size_t)M * 4);
  int*   part    = (int*)alloc(256 * 4);
  int*   csr     = (int*)alloc((size_t)E * 4);
  int*   flag    = (int*)alloc(4);
  if (off > ws_size) return;  // workspace too small: fail loudly via absmax

  // xb (bf16 x) lives in d_out scratch: dead before k_scatter writes out.
  short* xb = (short*)d_out;   // 51.2MB <= out's 102.4MB

  (void)hipMemsetAsync(outdeg, 0, (size_t)M * 4, stream);
  (void)hipMemsetAsync(indeg, 0, (size_t)M * 4, stream);
  k_flag<<<1, 64, 0, stream>>>(e32, flag);
  k_convW<<<(N_DIM * K_DIM / 4 + 255) / 256, 256, 0, stream>>>(W, Wb);
  long long totalx = (long long)M * K_DIM;
  k_convX<<<(int)((totalx / 8 + 255) / 256), 256, 0, stream>>>(x, xb, totalx);
  k_hist<<<(E + 255) / 256, 256, 0, stream>>>(e32, flag, outdeg, indeg, E);
  k_dis<<<(M + 255) / 256, 256, 0, stream>>>(outdeg, dis, M);
  int nscan = (M + 255) / 256;  // 196 (must be <= 256)
  k_scan_a<<<nscan, 256, 0, stream>>>(indeg, part, M);
  k_scan_b<<<1, 256, 0, stream>>>(part, nscan, rstart, M);
  k_scan_c<<<nscan, 256, 0, stream>>>(indeg, part, rstart, cursor, M);
  k_fill<<<(E + 255) / 256, 256, 0, stream>>>(e32, flag, cursor, csr, E);
  int nmc = (M + 127) / 128;     // 391 M-chunks
  k_gemm<<<nmc * 4, 256, 0, stream>>>(xb, Wb, bias, h, M);
  k_scatter<<<(M + 3) / 4, 256, 0, stream>>>(h, dis, rstart, csr, out, M);
}